// Round 1
// 1309.773 us; speedup vs baseline: 1.0177x; 1.0177x over previous
//
#include <hip/hip_runtime.h>

// Spatially-varying 17x17 blur.
// img:     (B=4, C=3, 272, 272) fp32, pre-padded
// kernels: (16, 1, 289, 65536) fp32, per-pixel taps (normalized)
// idx:     scalar int (device)
// out:     (4, 3, 256, 256) fp32
//
// R1: occupancy fix. Previous version used one thread per pixel x 12 (b,c)
// channels -> grid of 256 blocks = 1 block/CU = 1 wave/SIMD (12.5% occ),
// a serial ~7.9K-instruction thread with 3757 loads -> pure latency-bound
// (20x above the ~25 us cache/BW floor).
// Now: blockIdx.y = batch b (4-way split), each thread accumulates the 3
// channels of one batch. Grid = 1024 blocks = 4 blocks/CU = 16 waves/CU.
// kern slice is re-read by the 4 b-blocks, but they share an XCD
// (linear id = x + 256*y, 256 % 8 == 0) and are co-resident -> L2 hits;
// HBM kern traffic stays ~76 MB (read-once floor).
// - kern[k*P + p]: consecutive lanes -> consecutive addresses (coalesced).
// - img loads coalesced along x; img is 3.5 MB -> L2-resident per XCD.

#define KS 17
#define HP 256
#define WP 256
#define IW (WP + KS - 1)          // 272
#define IH (HP + KS - 1)          // 272
#define NPIX (HP * WP)            // 65536
#define CH_STRIDE (IW * IH)       // 73984

__global__ __launch_bounds__(256, 4) void blur_pixel_kernel(
    const float* __restrict__ img,
    const float* __restrict__ kernels,
    const int* __restrict__ idx_p,
    float* __restrict__ out)
{
    const int p = blockIdx.x * 256 + threadIdx.x;   // pixel id, one row per block
    const int b = blockIdx.y;                       // batch 0..3
    const int y = p >> 8;                           // WP == 256
    const int x = p & 255;

    // kernels[idx, 0, k, p]
    const float* kern = kernels + (long)idx_p[0] * (long)(KS * KS) * (long)NPIX + p;
    // img[b, 0, y, x]
    const float* imgp = img + (long)b * 3 * CH_STRIDE + y * IW + x;

    float a0 = 0.0f, a1 = 0.0f, a2 = 0.0f;

    for (int kh = 0; kh < KS; ++kh) {
        const float* krow = kern + (long)(kh * KS) * NPIX;
        const float* irow = imgp + kh * IW;
#pragma unroll
        for (int kw = 0; kw < KS; ++kw) {
            const float w = krow[(long)kw * NPIX];
            a0 = fmaf(w, irow[kw], a0);
            a1 = fmaf(w, irow[CH_STRIDE + kw], a1);
            a2 = fmaf(w, irow[2 * CH_STRIDE + kw], a2);
        }
    }

    float* op = out + (long)b * 3 * NPIX + p;
    op[0]        = a0;
    op[NPIX]     = a1;
    op[2 * NPIX] = a2;
}

extern "C" void kernel_launch(void* const* d_in, const int* in_sizes, int n_in,
                              void* d_out, int out_size, void* d_ws, size_t ws_size,
                              hipStream_t stream) {
    const float* img     = (const float*)d_in[0];
    const float* kernels = (const float*)d_in[1];
    const int*   idx     = (const int*)d_in[2];
    float*       out     = (float*)d_out;

    blur_pixel_kernel<<<dim3(NPIX / 256, 4), dim3(256), 0, stream>>>(img, kernels, idx, out);
}